// Round 4
// baseline (866.704 us; speedup 1.0000x reference)
//
#include <hip/hip_runtime.h>
#include <stdint.h>

// ---------------------------------------------------------------------------
// Char segmentation loss — round 6.
// d_out: [0]=loss_low, [1]=loss_middle, [2..)=mask_low (512*27*1024 f32 0/1).
//
// R5 post-mortem: LDS scratch added ds latency to the dependent path and VGPR
// stayed at 100 (the 54 inter/s1 accumulators dominate) -> occupancy stuck at
// 20%, main 152 us. VALU work is only ~38 us and HBM ~45 us -> a latency-
// hidden version should run ~70 us.
// R6 (Plan T): kill the 54 accumulator VGPRs. Per channel, butterfly-reduce
// prob and prob*mf across the wave and accumulate into TWO lane-owned regs
// (lane c owns channel c). l[27] stays in regs (single global read, single
// __expf per channel-pixel — frozen per-element math). Summation regrouping
// only; prior regroupings (R1->R2, atomics) kept absmax 0.0. Mask writes
// move to a separate post-accumulation loop (low blocks only).
// launch_bounds(256,8) caps 64 VGPR — live set is ~50 now (unlike R3).
// ---------------------------------------------------------------------------

static __device__ __forceinline__ float wave_reduce_add(float v) {
  v += __shfl_xor(v, 1, 64);
  v += __shfl_xor(v, 2, 64);
  v += __shfl_xor(v, 4, 64);
  v += __shfl_xor(v, 8, 64);
  v += __shfl_xor(v, 16, 64);
  v += __shfl_xor(v, 32, 64);
  return v;
}

// Thresholded attention bits for one output column (src coord), replicating
// jax.image.resize half-pixel bilinear (antialias=False); edge == clamp.
// Frozen from R1 (absmax was 0.0) — do not touch the rounding.
static __device__ __forceinline__ uint32_t attn_bits(const float* sattn, float src,
                                                     int lens, float alpha) {
  const int k0 = (int)floorf(src);
  uint32_t bits = 0u;
  if (k0 < 0 || k0 >= 31) {
    const int kk = (k0 < 0) ? 0 : 31;
    for (int c = 0; c < 26; ++c) {
      float v = (c < lens) ? sattn[c * 32 + kk] : 0.0f;
      if (v > alpha) bits |= (1u << c);
    }
  } else {
    const float frac = src - (float)k0;  // exact (multiples of 1/8)
    const float w1 = frac, w0 = 1.0f - frac;
    for (int c = 0; c < 26; ++c) {
      // __f*_rn: forbid fma contraction so we bit-match the reference dot.
      float v = __fadd_rn(__fmul_rn(w0, sattn[c * 32 + k0]),
                          __fmul_rn(w1, sattn[c * 32 + k0 + 1]));
      v = (c < lens) ? v : 0.0f;
      if (v > alpha) bits |= (1u << c);
    }
  }
  return bits;
}

// Prep: per-(b,x) attention bits for both widths; zero inter/s1 accumulators;
// compute s2[c] (mask pixel counts) analytically: for c>=1,
//   s2[c] = sum_x attn_bit(c,x) * colcount(x),  colcount(x) = sum_y fm(y,x)
// and s2[0] = HW - sum fm. Integer counts < 2^24 -> exact in f32, identical
// to per-pixel accumulation. Verified absmax 0.0 in R3/R4/R5.
__global__ __launch_bounds__(192) void prep_kernel(
    const float* __restrict__ attn,   // [512,26,32]
    const float* __restrict__ fore,   // [512,4096]
    const int* __restrict__ length,   // [512]
    const float* __restrict__ alpha_p,
    uint32_t* __restrict__ bits_mid,  // [512,128]
    uint32_t* __restrict__ bits_low,  // [512,64]
    float* __restrict__ acc_mid,      // [512,81]
    float* __restrict__ acc_low,      // [512,81]
    float* __restrict__ ce) {         // [2]
  __shared__ float sattn[26 * 32];
  __shared__ int scnt_mid[128];
  __shared__ int scnt_low[64];
  __shared__ uint32_t sbits_mid[128];
  __shared__ uint32_t sbits_low[64];
  const int b = blockIdx.x;
  const int t = threadIdx.x;
  for (int i = t; i < 832; i += 192) sattn[i] = attn[b * 832 + i];
  if (t < 54) { acc_mid[b * 81 + t] = 0.0f; acc_low[b * 81 + t] = 0.0f; }
  if (b == 0 && t >= 96 && t < 98) ce[t - 96] = 0.0f;

  const float* fb = fore + (size_t)b * 4096;
  if (t < 128) {
    // mid fm column count: fm = fore >= 0.4
    int cnt = 0;
    for (int y = 0; y < 32; ++y) cnt += (fb[y * 128 + t] >= 0.4f) ? 1 : 0;
    scnt_mid[t] = cnt;
  } else {
    // low fm column count: exact 4-tap half-pixel average, frozen rounding.
    const int x = t - 128;
    int cnt = 0;
    for (int y = 0; y < 16; ++y) {
      const float2* fr = (const float2*)(fb + (size_t)(2 * y) * 128 + 2 * x);
      const float2 f0 = fr[0];
      const float2 f1 = fr[64];
      const float t0 = __fadd_rn(0.5f * f0.x, 0.5f * f1.x);
      const float t1 = __fadd_rn(0.5f * f0.y, 0.5f * f1.y);
      const float fmv = __fadd_rn(0.5f * t0, 0.5f * t1);
      cnt += (fmv >= 0.4f) ? 1 : 0;
    }
    scnt_low[x] = cnt;
  }
  __syncthreads();

  const float alpha = alpha_p[0];
  const int lens = length[b] - 1;
  if (t < 128) {
    const float src = 0.25f * (float)t - 0.375f;  // 128 -> 32
    const uint32_t bits = attn_bits(sattn, src, lens, alpha);
    bits_mid[b * 128 + t] = bits;
    sbits_mid[t] = bits;
  } else {
    const int x = t - 128;
    const float src = 0.5f * (float)x - 0.25f;    // 64 -> 32
    const uint32_t bits = attn_bits(sattn, src, lens, alpha);
    bits_low[b * 64 + x] = bits;
    sbits_low[x] = bits;
  }
  __syncthreads();

  if (t < 27) {
    const int c = t;
    int s2;
    if (c == 0) {
      int tot = 0;
      for (int x = 0; x < 128; ++x) tot += scnt_mid[x];
      s2 = 4096 - tot;
    } else {
      s2 = 0;
      for (int x = 0; x < 128; ++x)
        s2 += (int)((sbits_mid[x] >> (c - 1)) & 1u) * scnt_mid[x];
    }
    acc_mid[b * 81 + 54 + c] = (float)s2;
  } else if (t >= 64 && t < 91) {
    const int c = t - 64;
    int s2;
    if (c == 0) {
      int tot = 0;
      for (int x = 0; x < 64; ++x) tot += scnt_low[x];
      s2 = 1024 - tot;
    } else {
      s2 = 0;
      for (int x = 0; x < 64; ++x)
        s2 += (int)((sbits_low[x] >> (c - 1)) & 1u) * scnt_low[x];
    }
    acc_low[b * 81 + 54 + c] = (float)s2;
  }
}

// Main: blocks [0,4096) = mid slices (8 per b), [4096,5120) = low (2 per b).
// Each block: 512 pixels, full 27-channel softmax. Dice partials are
// butterfly-reduced per channel and held in lane-owned registers (lane c
// owns channel c's inter and s1 partial) -> no 54-register accumulator
// arrays -> VGPR <= 64 -> 8 waves/SIMD.
__global__ __launch_bounds__(256, 8) void main_kernel(
    const float* __restrict__ cf_mid,   // [512,27,4096]
    const float* __restrict__ cf_low,   // [512,27,1024]
    const float* __restrict__ fore,     // [512,4096]
    float* __restrict__ out,
    const uint32_t* __restrict__ bits_mid,
    const uint32_t* __restrict__ bits_low,
    float* __restrict__ acc_mid,
    float* __restrict__ acc_low,
    float* __restrict__ ce) {
  const int t = threadIdx.x;
  const int lane = t & 63;
  const int wave = t >> 6;
  const int bid = blockIdx.x;
  const bool low = (bid >= 4096);
  int b, p0, W, HW;
  const float* cf;
  const uint32_t* bitsp;
  float* acc;
  if (low) {
    const int idx = bid - 4096;
    b = idx >> 1; p0 = (idx & 1) << 9; W = 64; HW = 1024;
    cf = cf_low; bitsp = bits_low + (size_t)b * 64; acc = acc_low;
  } else {
    b = bid >> 3; p0 = (bid & 7) << 9; W = 128; HW = 4096;
    cf = cf_mid; bitsp = bits_mid + (size_t)b * 128; acc = acc_mid;
  }
  const float* cfb = cf + (size_t)b * 27 * HW;
  const float* fb = fore + (size_t)b * 4096;
  float* mout = out + 2 + (size_t)b * 27 * 1024;  // low only

  float accI = 0.0f;  // lane c (c<27): running inter[c] partial for this wave
  float accS = 0.0f;  // lane c (c<27): running s1[c] partial for this wave
  float cesum = 0.0f;

  for (int k = 0; k < 2; ++k) {
    const int p = p0 + t + (k << 8);
    const int x = p & (W - 1);

    int fmw;
    if (low) {
      // fm_low: exact 4-tap half-pixel average, frozen from R1.
      const int y = p >> 6;
      const float2* fr = (const float2*)(fb + (size_t)(2 * y) * 128 + 2 * x);
      const float2 f0 = fr[0];
      const float2 f1 = fr[64];
      const float t0 = __fadd_rn(0.5f * f0.x, 0.5f * f1.x);
      const float t1 = __fadd_rn(0.5f * f0.y, 0.5f * f1.y);
      const float fmv = __fadd_rn(0.5f * t0, 0.5f * t1);
      fmw = (fmv >= 0.4f) ? 1 : 0;
    } else {
      fmw = (fb[p] >= 0.4f) ? 1 : 0;
    }

    const uint32_t bits = bitsp[x];
    const int target = fmw ? (int)__ffs(bits) : 0;
    const float* cp = cfb + p;

    // Pass 1: load once, cache in regs, running max + target logit.
    float l[27];
    float m = -1e30f, lt = 0.0f;
#pragma unroll
    for (int c = 0; c < 27; ++c) {
      const float v = cp[(size_t)c * HW];
      l[c] = v;
      m = fmaxf(m, v);
      lt = (c == target) ? v : lt;
    }

    // Pass 2: exp once, overwrite cache, accumulate sum.
    float s = 0.0f;
#pragma unroll
    for (int c = 0; c < 27; ++c) {
      const float e = __expf(l[c] - m);
      l[c] = e;
      s += e;
    }
    const float inv = 1.0f / s;
    cesum += (m + __logf(s) - lt);  // -log p(target)

    // Pass 3: per-channel wave reduction into lane-owned accumulators.
#pragma unroll
    for (int c = 0; c < 27; ++c) {
      const float prob = l[c] * inv;
      float mf;
      if (c == 0) mf = (float)(1 - fmw);
      else mf = (float)(((bits >> (c - 1)) & 1u) & (uint32_t)fmw);
      const float rS = wave_reduce_add(prob);
      const float rI = wave_reduce_add(prob * mf);
      accS += (lane == c) ? rS : 0.0f;
      accI += (lane == c) ? rI : 0.0f;
    }

    // Mask write (low only), outside the accumulate loop: mf from bits/fmw.
    if (low) {
#pragma unroll
      for (int c = 0; c < 27; ++c) {
        float mf;
        if (c == 0) mf = (float)(1 - fmw);
        else mf = (float)(((bits >> (c - 1)) & 1u) & (uint32_t)fmw);
        mout[(size_t)c * 1024 + p] = mf;
      }
    }
  }

  // cross-wave LDS + one atomicAdd per (b,c,slot)
  __shared__ float red[4][55];
  cesum = wave_reduce_add(cesum);
  if (lane < 27) {
    red[wave][lane] = accI;        // inter partials -> slots [0,27)
    red[wave][27 + lane] = accS;   // s1 partials    -> slots [27,54)
  }
  if (lane == 63) red[wave][54] = cesum;
  __syncthreads();
  if (t < 55) {
    const float v = red[0][t] + red[1][t] + red[2][t] + red[3][t];
    if (t == 54) atomicAdd(&ce[low ? 0 : 1], v);
    else atomicAdd(&acc[(size_t)b * 81 + t], v);
  }
}

// Final: block 0 -> loss_low (out[0]), block 1 -> loss_middle (out[1]).
__global__ __launch_bounds__(256) void final_kernel(
    const float* __restrict__ acc_mid,
    const float* __restrict__ acc_low,
    const float* __restrict__ ce,
    const int* __restrict__ length,
    float* __restrict__ out) {
  const int B = blockIdx.x;  // 0=low, 1=mid
  const float* acc = (B == 0) ? acc_low : acc_mid;
  const float hw = (B == 0) ? 1024.0f : 4096.0f;
  const int t = threadIdx.x;
  float dsum = 0.0f;
  for (int b = t; b < 512; b += 256) {
    const int lens = length[b] - 1;
    const float* a = acc + (size_t)b * 81;
    float d = 0.0f;
    for (int c = 1; c < 27; ++c) {
      const float I = a[c], S1 = a[27 + c], S2 = a[54 + c];
      const float score = (2.0f * I + 1.0f) / (S1 + S2 + 1.0f);
      if (c <= lens) d += (1.0f - score);
    }
    dsum += d / (float)lens;
  }
  __shared__ float red[4];
  const int wave = t >> 6, lane = t & 63;
  dsum = wave_reduce_add(dsum);
  if (lane == 0) red[wave] = dsum;
  __syncthreads();
  if (t == 0) {
    const float dice = red[0] + red[1] + red[2] + red[3];
    out[B] = dice * (1.0f / 512.0f) + ce[B] * (1.0f / (512.0f * hw));
  }
}

extern "C" void kernel_launch(void* const* d_in, const int* in_sizes, int n_in,
                              void* d_out, int out_size, void* d_ws, size_t ws_size,
                              hipStream_t stream) {
  const float* cf_mid = (const float*)d_in[0];  // [512,27,32,128]
  const float* cf_low = (const float*)d_in[1];  // [512,27,16,64]
  const float* attn   = (const float*)d_in[2];  // [512,26,32]
  const float* fore   = (const float*)d_in[3];  // [512,1,32,128]
  const int*   length = (const int*)d_in[4];    // [512]
  const float* alpha  = (const float*)d_in[5];  // scalar
  float* out = (float*)d_out;

  // ws layout
  uint32_t* bits_mid = (uint32_t*)d_ws;                   // 512*128
  uint32_t* bits_low = bits_mid + 512 * 128;              // 512*64
  float* acc_mid = (float*)(bits_low + 512 * 64);         // 512*81
  float* acc_low = acc_mid + 512 * 81;                    // 512*81
  float* ce = acc_low + 512 * 81;                         // 2

  hipLaunchKernelGGL(prep_kernel, dim3(512), dim3(192), 0, stream,
                     attn, fore, length, alpha, bits_mid, bits_low,
                     acc_mid, acc_low, ce);
  hipLaunchKernelGGL(main_kernel, dim3(5120), dim3(256), 0, stream,
                     cf_mid, cf_low, fore, out, bits_mid, bits_low,
                     acc_mid, acc_low, ce);
  hipLaunchKernelGGL(final_kernel, dim3(2), dim3(256), 0, stream,
                     acc_mid, acc_low, ce, length, out);
}

// Round 5
// 700.415 us; speedup vs baseline: 1.2374x; 1.2374x over previous
//
#include <hip/hip_runtime.h>
#include <stdint.h>

// ---------------------------------------------------------------------------
// Char segmentation loss — round 7.
// d_out: [0]=loss_low, [1]=loss_middle, [2..)=mask_low (512*27*1024 f32 0/1).
//
// R6 post-mortem: launch_bounds(256,8) == 32-VGPR cap (empirical: (256,4)->64,
// (256,8)->32) -> catastrophic spills (WRITE 1.36 GB). Per-pixel butterfly
// reduction also structurally too expensive (324 DS-ops/wave-iter).
// R7: channel-chunked two-phase. Phase A per pixel = R2's pass1+2 (27 loads
// into short-lived regs, m/inv/cesum). Phase B = 3 groups x 9 channels:
// re-read logits (L2/L3 hits), recompute exp(v-m)*inv (bit-identical),
// accumulate into 18 regs, ONE wave-reduce per block per group (R2's exact
// butterfly+LDS+atomic structure). Peak live ~45 regs -> (256,4) 64-reg cap
// -> 8 waves/SIMD, no spills. All arithmetic, accumulation order, reduction
// order identical to R2 (absmax 0.0); only value lifetimes changed.
// ---------------------------------------------------------------------------

static __device__ __forceinline__ float wave_reduce_add(float v) {
  v += __shfl_xor(v, 1, 64);
  v += __shfl_xor(v, 2, 64);
  v += __shfl_xor(v, 4, 64);
  v += __shfl_xor(v, 8, 64);
  v += __shfl_xor(v, 16, 64);
  v += __shfl_xor(v, 32, 64);
  return v;
}

// Thresholded attention bits for one output column (src coord), replicating
// jax.image.resize half-pixel bilinear (antialias=False); edge == clamp.
// Frozen from R1 (absmax was 0.0) — do not touch the rounding.
static __device__ __forceinline__ uint32_t attn_bits(const float* sattn, float src,
                                                     int lens, float alpha) {
  const int k0 = (int)floorf(src);
  uint32_t bits = 0u;
  if (k0 < 0 || k0 >= 31) {
    const int kk = (k0 < 0) ? 0 : 31;
    for (int c = 0; c < 26; ++c) {
      float v = (c < lens) ? sattn[c * 32 + kk] : 0.0f;
      if (v > alpha) bits |= (1u << c);
    }
  } else {
    const float frac = src - (float)k0;  // exact (multiples of 1/8)
    const float w1 = frac, w0 = 1.0f - frac;
    for (int c = 0; c < 26; ++c) {
      // __f*_rn: forbid fma contraction so we bit-match the reference dot.
      float v = __fadd_rn(__fmul_rn(w0, sattn[c * 32 + k0]),
                          __fmul_rn(w1, sattn[c * 32 + k0 + 1]));
      v = (c < lens) ? v : 0.0f;
      if (v > alpha) bits |= (1u << c);
    }
  }
  return bits;
}

// Prep: per-(b,x) attention bits for both widths; zero inter/s1 accumulators;
// compute s2[c] (mask pixel counts) analytically: for c>=1,
//   s2[c] = sum_x attn_bit(c,x) * colcount(x),  colcount(x) = sum_y fm(y,x)
// and s2[0] = HW - sum fm. Integer counts < 2^24 -> exact in f32, identical
// to per-pixel accumulation. Verified absmax 0.0 in R3..R6.
__global__ __launch_bounds__(192) void prep_kernel(
    const float* __restrict__ attn,   // [512,26,32]
    const float* __restrict__ fore,   // [512,4096]
    const int* __restrict__ length,   // [512]
    const float* __restrict__ alpha_p,
    uint32_t* __restrict__ bits_mid,  // [512,128]
    uint32_t* __restrict__ bits_low,  // [512,64]
    float* __restrict__ acc_mid,      // [512,81]
    float* __restrict__ acc_low,      // [512,81]
    float* __restrict__ ce) {         // [2]
  __shared__ float sattn[26 * 32];
  __shared__ int scnt_mid[128];
  __shared__ int scnt_low[64];
  __shared__ uint32_t sbits_mid[128];
  __shared__ uint32_t sbits_low[64];
  const int b = blockIdx.x;
  const int t = threadIdx.x;
  for (int i = t; i < 832; i += 192) sattn[i] = attn[b * 832 + i];
  if (t < 54) { acc_mid[b * 81 + t] = 0.0f; acc_low[b * 81 + t] = 0.0f; }
  if (b == 0 && t >= 96 && t < 98) ce[t - 96] = 0.0f;

  const float* fb = fore + (size_t)b * 4096;
  if (t < 128) {
    // mid fm column count: fm = fore >= 0.4
    int cnt = 0;
    for (int y = 0; y < 32; ++y) cnt += (fb[y * 128 + t] >= 0.4f) ? 1 : 0;
    scnt_mid[t] = cnt;
  } else {
    // low fm column count: exact 4-tap half-pixel average, frozen rounding.
    const int x = t - 128;
    int cnt = 0;
    for (int y = 0; y < 16; ++y) {
      const float2* fr = (const float2*)(fb + (size_t)(2 * y) * 128 + 2 * x);
      const float2 f0 = fr[0];
      const float2 f1 = fr[64];
      const float t0 = __fadd_rn(0.5f * f0.x, 0.5f * f1.x);
      const float t1 = __fadd_rn(0.5f * f0.y, 0.5f * f1.y);
      const float fmv = __fadd_rn(0.5f * t0, 0.5f * t1);
      cnt += (fmv >= 0.4f) ? 1 : 0;
    }
    scnt_low[x] = cnt;
  }
  __syncthreads();

  const float alpha = alpha_p[0];
  const int lens = length[b] - 1;
  if (t < 128) {
    const float src = 0.25f * (float)t - 0.375f;  // 128 -> 32
    const uint32_t bits = attn_bits(sattn, src, lens, alpha);
    bits_mid[b * 128 + t] = bits;
    sbits_mid[t] = bits;
  } else {
    const int x = t - 128;
    const float src = 0.5f * (float)x - 0.25f;    // 64 -> 32
    const uint32_t bits = attn_bits(sattn, src, lens, alpha);
    bits_low[b * 64 + x] = bits;
    sbits_low[x] = bits;
  }
  __syncthreads();

  if (t < 27) {
    const int c = t;
    int s2;
    if (c == 0) {
      int tot = 0;
      for (int x = 0; x < 128; ++x) tot += scnt_mid[x];
      s2 = 4096 - tot;
    } else {
      s2 = 0;
      for (int x = 0; x < 128; ++x)
        s2 += (int)((sbits_mid[x] >> (c - 1)) & 1u) * scnt_mid[x];
    }
    acc_mid[b * 81 + 54 + c] = (float)s2;
  } else if (t >= 64 && t < 91) {
    const int c = t - 64;
    int s2;
    if (c == 0) {
      int tot = 0;
      for (int x = 0; x < 64; ++x) tot += scnt_low[x];
      s2 = 1024 - tot;
    } else {
      s2 = 0;
      for (int x = 0; x < 64; ++x)
        s2 += (int)((sbits_low[x] >> (c - 1)) & 1u) * scnt_low[x];
    }
    acc_low[b * 81 + 54 + c] = (float)s2;
  }
}

// Main: blocks [0,4096) = mid slices (8 per b), [4096,5120) = low (2 per b).
// Each block: 512 pixels. Phase A: per-pixel softmax stats (m, inv, ce) with
// transient 27-reg logit cache. Phase B: 3 channel-groups x 9, re-read +
// recompute probs, 18 accumulator regs, one wave-reduction per group.
__global__ __launch_bounds__(256, 4) void main_kernel(
    const float* __restrict__ cf_mid,   // [512,27,4096]
    const float* __restrict__ cf_low,   // [512,27,1024]
    const float* __restrict__ fore,     // [512,4096]
    float* __restrict__ out,
    const uint32_t* __restrict__ bits_mid,
    const uint32_t* __restrict__ bits_low,
    float* __restrict__ acc_mid,
    float* __restrict__ acc_low,
    float* __restrict__ ce) {
  const int t = threadIdx.x;
  const int lane = t & 63;
  const int wave = t >> 6;
  const int bid = blockIdx.x;
  const bool low = (bid >= 4096);
  int b, p0, W, HW;
  const float* cf;
  const uint32_t* bitsp;
  float* acc;
  if (low) {
    const int idx = bid - 4096;
    b = idx >> 1; p0 = (idx & 1) << 9; W = 64; HW = 1024;
    cf = cf_low; bitsp = bits_low + (size_t)b * 64; acc = acc_low;
  } else {
    b = bid >> 3; p0 = (bid & 7) << 9; W = 128; HW = 4096;
    cf = cf_mid; bitsp = bits_mid + (size_t)b * 128; acc = acc_mid;
  }
  const float* cfb = cf + (size_t)b * 27 * HW;
  const float* fb = fore + (size_t)b * 4096;
  float* mout = out + 2 + (size_t)b * 27 * 1024;  // low only

  float cesum = 0.0f;
  float m2[2], inv2[2];
  int fmw2[2];
  uint32_t bits2[2];

  // ---- Phase A: per-pixel softmax stats (R2's pass 1+2, bit-identical) ----
#pragma unroll
  for (int k = 0; k < 2; ++k) {
    const int p = p0 + t + (k << 8);
    const int x = p & (W - 1);

    int fmw;
    if (low) {
      // fm_low: exact 4-tap half-pixel average, frozen from R1.
      const int y = p >> 6;
      const float2* fr = (const float2*)(fb + (size_t)(2 * y) * 128 + 2 * x);
      const float2 f0 = fr[0];
      const float2 f1 = fr[64];
      const float t0 = __fadd_rn(0.5f * f0.x, 0.5f * f1.x);
      const float t1 = __fadd_rn(0.5f * f0.y, 0.5f * f1.y);
      const float fmv = __fadd_rn(0.5f * t0, 0.5f * t1);
      fmw = (fmv >= 0.4f) ? 1 : 0;
    } else {
      fmw = (fb[p] >= 0.4f) ? 1 : 0;
    }

    const uint32_t bits = bitsp[x];
    const int target = fmw ? (int)__ffs(bits) : 0;
    const float* cp = cfb + p;

    float l[27];  // transient: dead after this k-iteration
    float m = -1e30f, lt = 0.0f;
#pragma unroll
    for (int c = 0; c < 27; ++c) {
      const float v = cp[(size_t)c * HW];
      l[c] = v;
      m = fmaxf(m, v);
      lt = (c == target) ? v : lt;
    }
    float s = 0.0f;
#pragma unroll
    for (int c = 0; c < 27; ++c) s += __expf(l[c] - m);
    const float inv = 1.0f / s;
    cesum += (m + __logf(s) - lt);  // -log p(target)

    m2[k] = m; inv2[k] = inv; fmw2[k] = fmw; bits2[k] = bits;
  }

  // ---- mask_low writes (bits/fmw only; store order irrelevant) ----
  if (low) {
#pragma unroll
    for (int k = 0; k < 2; ++k) {
      const int p = p0 + t + (k << 8);
      const int fmw = fmw2[k];
      const uint32_t bits = bits2[k];
#pragma unroll
      for (int c = 0; c < 27; ++c) {
        float mf;
        if (c == 0) mf = (float)(1 - fmw);
        else mf = (float)(((bits >> (c - 1)) & 1u) & (uint32_t)fmw);
        mout[(size_t)c * 1024 + p] = mf;
      }
    }
  }

  asm volatile("" ::: "memory");  // forbid load-CSE across the phase boundary

  // ---- Phase B: chunked accumulation, 9 channels per group ----
  __shared__ float red[4][55];
#pragma unroll
  for (int g = 0; g < 3; ++g) {
    float aS[9], aI[9];
#pragma unroll
    for (int j = 0; j < 9; ++j) { aS[j] = 0.0f; aI[j] = 0.0f; }
#pragma unroll
    for (int k = 0; k < 2; ++k) {
      const int p = p0 + t + (k << 8);
      const float m = m2[k], inv = inv2[k];
      const int fmw = fmw2[k];
      const uint32_t bits = bits2[k];
      const float* cp = cfb + p;
#pragma unroll
      for (int j = 0; j < 9; ++j) {
        const int c = g * 9 + j;
        const float v = cp[(size_t)c * HW];
        const float prob = __expf(v - m) * inv;  // bit-identical to cached e*inv
        aS[j] += prob;
        float mf;
        if (c == 0) mf = (float)(1 - fmw);
        else mf = (float)(((bits >> (c - 1)) & 1u) & (uint32_t)fmw);
        aI[j] += prob * mf;
      }
    }
    // One wave-reduction per group per block (R2's exact butterfly).
#pragma unroll
    for (int j = 0; j < 9; ++j) {
      const float rI = wave_reduce_add(aI[j]);
      const float rS = wave_reduce_add(aS[j]);
      if (lane == 0) {
        red[wave][g * 9 + j] = rI;
        red[wave][27 + g * 9 + j] = rS;
      }
    }
  }
  cesum = wave_reduce_add(cesum);
  if (lane == 0) red[wave][54] = cesum;
  __syncthreads();
  if (t < 55) {
    const float v = red[0][t] + red[1][t] + red[2][t] + red[3][t];
    if (t == 54) atomicAdd(&ce[low ? 0 : 1], v);
    else atomicAdd(&acc[(size_t)b * 81 + t], v);
  }
}

// Final: block 0 -> loss_low (out[0]), block 1 -> loss_middle (out[1]).
__global__ __launch_bounds__(256) void final_kernel(
    const float* __restrict__ acc_mid,
    const float* __restrict__ acc_low,
    const float* __restrict__ ce,
    const int* __restrict__ length,
    float* __restrict__ out) {
  const int B = blockIdx.x;  // 0=low, 1=mid
  const float* acc = (B == 0) ? acc_low : acc_mid;
  const float hw = (B == 0) ? 1024.0f : 4096.0f;
  const int t = threadIdx.x;
  float dsum = 0.0f;
  for (int b = t; b < 512; b += 256) {
    const int lens = length[b] - 1;
    const float* a = acc + (size_t)b * 81;
    float d = 0.0f;
    for (int c = 1; c < 27; ++c) {
      const float I = a[c], S1 = a[27 + c], S2 = a[54 + c];
      const float score = (2.0f * I + 1.0f) / (S1 + S2 + 1.0f);
      if (c <= lens) d += (1.0f - score);
    }
    dsum += d / (float)lens;
  }
  __shared__ float red[4];
  const int wave = t >> 6, lane = t & 63;
  dsum = wave_reduce_add(dsum);
  if (lane == 0) red[wave] = dsum;
  __syncthreads();
  if (t == 0) {
    const float dice = red[0] + red[1] + red[2] + red[3];
    out[B] = dice * (1.0f / 512.0f) + ce[B] * (1.0f / (512.0f * hw));
  }
}

extern "C" void kernel_launch(void* const* d_in, const int* in_sizes, int n_in,
                              void* d_out, int out_size, void* d_ws, size_t ws_size,
                              hipStream_t stream) {
  const float* cf_mid = (const float*)d_in[0];  // [512,27,32,128]
  const float* cf_low = (const float*)d_in[1];  // [512,27,16,64]
  const float* attn   = (const float*)d_in[2];  // [512,26,32]
  const float* fore   = (const float*)d_in[3];  // [512,1,32,128]
  const int*   length = (const int*)d_in[4];    // [512]
  const float* alpha  = (const float*)d_in[5];  // scalar
  float* out = (float*)d_out;

  // ws layout
  uint32_t* bits_mid = (uint32_t*)d_ws;                   // 512*128
  uint32_t* bits_low = bits_mid + 512 * 128;              // 512*64
  float* acc_mid = (float*)(bits_low + 512 * 64);         // 512*81
  float* acc_low = acc_mid + 512 * 81;                    // 512*81
  float* ce = acc_low + 512 * 81;                         // 2

  hipLaunchKernelGGL(prep_kernel, dim3(512), dim3(192), 0, stream,
                     attn, fore, length, alpha, bits_mid, bits_low,
                     acc_mid, acc_low, ce);
  hipLaunchKernelGGL(main_kernel, dim3(5120), dim3(256), 0, stream,
                     cf_mid, cf_low, fore, out, bits_mid, bits_low,
                     acc_mid, acc_low, ce);
  hipLaunchKernelGGL(final_kernel, dim3(2), dim3(256), 0, stream,
                     acc_mid, acc_low, ce, length, out);
}

// Round 6
// 535.748 us; speedup vs baseline: 1.6177x; 1.3074x over previous
//
#include <hip/hip_runtime.h>
#include <stdint.h>

// ---------------------------------------------------------------------------
// Char segmentation loss — round 8.
// d_out: [0]=loss_low, [1]=loss_middle, [2..)=mask_low (512*27*1024 f32 0/1).
//
// R7 post-mortem: compiler batches all 27 Phase-A loads (27 live regs); under
// the (256,4)=64-reg cap it spilled (WRITE 636 MB) instead of serializing.
// Rule confirmed: never force a min-waves cap (R3/R6/R7 all lost). R4's
// uncapped 3-pass recompute (133 us, zero spill, FETCH ~148 MB -> re-reads
// are L2/L3-absorbed) is the base.
// R8: shrink live regions STRUCTURALLY so the compiler lands low on its own:
//  - Phase A max & exp-sum sweeps each split into 13/14-channel load batches
//    with asm memory clobbers between (fold order c=0..26 unchanged).
//  - Phase B = 3 groups x 9 channels (18 acc regs), clobbers between groups.
// No min-waves arg. All per-element math / fold orders / reduction structure
// identical to R4/R7 (absmax 0.0) — only value lifetimes change.
// ---------------------------------------------------------------------------

static __device__ __forceinline__ float wave_reduce_add(float v) {
  v += __shfl_xor(v, 1, 64);
  v += __shfl_xor(v, 2, 64);
  v += __shfl_xor(v, 4, 64);
  v += __shfl_xor(v, 8, 64);
  v += __shfl_xor(v, 16, 64);
  v += __shfl_xor(v, 32, 64);
  return v;
}

// Thresholded attention bits for one output column (src coord), replicating
// jax.image.resize half-pixel bilinear (antialias=False); edge == clamp.
// Frozen from R1 (absmax was 0.0) — do not touch the rounding.
static __device__ __forceinline__ uint32_t attn_bits(const float* sattn, float src,
                                                     int lens, float alpha) {
  const int k0 = (int)floorf(src);
  uint32_t bits = 0u;
  if (k0 < 0 || k0 >= 31) {
    const int kk = (k0 < 0) ? 0 : 31;
    for (int c = 0; c < 26; ++c) {
      float v = (c < lens) ? sattn[c * 32 + kk] : 0.0f;
      if (v > alpha) bits |= (1u << c);
    }
  } else {
    const float frac = src - (float)k0;  // exact (multiples of 1/8)
    const float w1 = frac, w0 = 1.0f - frac;
    for (int c = 0; c < 26; ++c) {
      // __f*_rn: forbid fma contraction so we bit-match the reference dot.
      float v = __fadd_rn(__fmul_rn(w0, sattn[c * 32 + k0]),
                          __fmul_rn(w1, sattn[c * 32 + k0 + 1]));
      v = (c < lens) ? v : 0.0f;
      if (v > alpha) bits |= (1u << c);
    }
  }
  return bits;
}

// Prep: per-(b,x) attention bits for both widths; zero inter/s1 accumulators;
// compute s2[c] (mask pixel counts) analytically: for c>=1,
//   s2[c] = sum_x attn_bit(c,x) * colcount(x),  colcount(x) = sum_y fm(y,x)
// and s2[0] = HW - sum fm. Integer counts < 2^24 -> exact in f32, identical
// to per-pixel accumulation. Verified absmax 0.0 in R3..R7.
__global__ __launch_bounds__(192) void prep_kernel(
    const float* __restrict__ attn,   // [512,26,32]
    const float* __restrict__ fore,   // [512,4096]
    const int* __restrict__ length,   // [512]
    const float* __restrict__ alpha_p,
    uint32_t* __restrict__ bits_mid,  // [512,128]
    uint32_t* __restrict__ bits_low,  // [512,64]
    float* __restrict__ acc_mid,      // [512,81]
    float* __restrict__ acc_low,      // [512,81]
    float* __restrict__ ce) {         // [2]
  __shared__ float sattn[26 * 32];
  __shared__ int scnt_mid[128];
  __shared__ int scnt_low[64];
  __shared__ uint32_t sbits_mid[128];
  __shared__ uint32_t sbits_low[64];
  const int b = blockIdx.x;
  const int t = threadIdx.x;
  for (int i = t; i < 832; i += 192) sattn[i] = attn[b * 832 + i];
  if (t < 54) { acc_mid[b * 81 + t] = 0.0f; acc_low[b * 81 + t] = 0.0f; }
  if (b == 0 && t >= 96 && t < 98) ce[t - 96] = 0.0f;

  const float* fb = fore + (size_t)b * 4096;
  if (t < 128) {
    // mid fm column count: fm = fore >= 0.4
    int cnt = 0;
    for (int y = 0; y < 32; ++y) cnt += (fb[y * 128 + t] >= 0.4f) ? 1 : 0;
    scnt_mid[t] = cnt;
  } else {
    // low fm column count: exact 4-tap half-pixel average, frozen rounding.
    const int x = t - 128;
    int cnt = 0;
    for (int y = 0; y < 16; ++y) {
      const float2* fr = (const float2*)(fb + (size_t)(2 * y) * 128 + 2 * x);
      const float2 f0 = fr[0];
      const float2 f1 = fr[64];
      const float t0 = __fadd_rn(0.5f * f0.x, 0.5f * f1.x);
      const float t1 = __fadd_rn(0.5f * f0.y, 0.5f * f1.y);
      const float fmv = __fadd_rn(0.5f * t0, 0.5f * t1);
      cnt += (fmv >= 0.4f) ? 1 : 0;
    }
    scnt_low[x] = cnt;
  }
  __syncthreads();

  const float alpha = alpha_p[0];
  const int lens = length[b] - 1;
  if (t < 128) {
    const float src = 0.25f * (float)t - 0.375f;  // 128 -> 32
    const uint32_t bits = attn_bits(sattn, src, lens, alpha);
    bits_mid[b * 128 + t] = bits;
    sbits_mid[t] = bits;
  } else {
    const int x = t - 128;
    const float src = 0.5f * (float)x - 0.25f;    // 64 -> 32
    const uint32_t bits = attn_bits(sattn, src, lens, alpha);
    bits_low[b * 64 + x] = bits;
    sbits_low[x] = bits;
  }
  __syncthreads();

  if (t < 27) {
    const int c = t;
    int s2;
    if (c == 0) {
      int tot = 0;
      for (int x = 0; x < 128; ++x) tot += scnt_mid[x];
      s2 = 4096 - tot;
    } else {
      s2 = 0;
      for (int x = 0; x < 128; ++x)
        s2 += (int)((sbits_mid[x] >> (c - 1)) & 1u) * scnt_mid[x];
    }
    acc_mid[b * 81 + 54 + c] = (float)s2;
  } else if (t >= 64 && t < 91) {
    const int c = t - 64;
    int s2;
    if (c == 0) {
      int tot = 0;
      for (int x = 0; x < 64; ++x) tot += scnt_low[x];
      s2 = 1024 - tot;
    } else {
      s2 = 0;
      for (int x = 0; x < 64; ++x)
        s2 += (int)((sbits_low[x] >> (c - 1)) & 1u) * scnt_low[x];
    }
    acc_low[b * 81 + 54 + c] = (float)s2;
  }
}

// Main: blocks [0,4096) = mid slices (8 per b), [4096,5120) = low (2 per b).
// Each block: 512 pixels. Phase A: per-pixel softmax stats with 13/14-channel
// load batches (clobber-separated -> small live sets). Phase B: 3 channel
// groups x 9, re-read + recompute probs, 18 accumulator regs, one
// wave-reduction per group. No min-waves cap.
__global__ __launch_bounds__(256) void main_kernel(
    const float* __restrict__ cf_mid,   // [512,27,4096]
    const float* __restrict__ cf_low,   // [512,27,1024]
    const float* __restrict__ fore,     // [512,4096]
    float* __restrict__ out,
    const uint32_t* __restrict__ bits_mid,
    const uint32_t* __restrict__ bits_low,
    float* __restrict__ acc_mid,
    float* __restrict__ acc_low,
    float* __restrict__ ce) {
  const int t = threadIdx.x;
  const int lane = t & 63;
  const int wave = t >> 6;
  const int bid = blockIdx.x;
  const bool low = (bid >= 4096);
  int b, p0, W, HW;
  const float* cf;
  const uint32_t* bitsp;
  float* acc;
  if (low) {
    const int idx = bid - 4096;
    b = idx >> 1; p0 = (idx & 1) << 9; W = 64; HW = 1024;
    cf = cf_low; bitsp = bits_low + (size_t)b * 64; acc = acc_low;
  } else {
    b = bid >> 3; p0 = (bid & 7) << 9; W = 128; HW = 4096;
    cf = cf_mid; bitsp = bits_mid + (size_t)b * 128; acc = acc_mid;
  }
  const float* cfb = cf + (size_t)b * 27 * HW;
  const float* fb = fore + (size_t)b * 4096;
  float* mout = out + 2 + (size_t)b * 27 * 1024;  // low only

  float cesum = 0.0f;
  float m2[2], inv2[2];
  int fmw2[2];
  uint32_t bits2[2];

  // ---- Phase A: per-pixel softmax stats, small load batches ----
#pragma unroll
  for (int k = 0; k < 2; ++k) {
    const int p = p0 + t + (k << 8);
    const int x = p & (W - 1);

    int fmw;
    if (low) {
      // fm_low: exact 4-tap half-pixel average, frozen from R1.
      const int y = p >> 6;
      const float2* fr = (const float2*)(fb + (size_t)(2 * y) * 128 + 2 * x);
      const float2 f0 = fr[0];
      const float2 f1 = fr[64];
      const float t0 = __fadd_rn(0.5f * f0.x, 0.5f * f1.x);
      const float t1 = __fadd_rn(0.5f * f0.y, 0.5f * f1.y);
      const float fmv = __fadd_rn(0.5f * t0, 0.5f * t1);
      fmw = (fmv >= 0.4f) ? 1 : 0;
    } else {
      fmw = (fb[p] >= 0.4f) ? 1 : 0;
    }

    const uint32_t bits = bitsp[x];
    const int target = fmw ? (int)__ffs(bits) : 0;
    const float* cp = cfb + p;

    // Max + target logit: fold order c=0..26 preserved; two load batches.
    float m = -1e30f, lt = 0.0f;
#pragma unroll
    for (int c = 0; c < 14; ++c) {
      const float v = cp[(size_t)c * HW];
      m = fmaxf(m, v);
      lt = (c == target) ? v : lt;
    }
    asm volatile("" ::: "memory");  // batch boundary: cap loads in flight
#pragma unroll
    for (int c = 14; c < 27; ++c) {
      const float v = cp[(size_t)c * HW];
      m = fmaxf(m, v);
      lt = (c == target) ? v : lt;
    }
    asm volatile("" ::: "memory");

    // Exp-sum: fold order c=0..26 preserved; two load batches; re-read cf.
    float s = 0.0f;
#pragma unroll
    for (int c = 0; c < 14; ++c) s += __expf(cp[(size_t)c * HW] - m);
    asm volatile("" ::: "memory");
#pragma unroll
    for (int c = 14; c < 27; ++c) s += __expf(cp[(size_t)c * HW] - m);
    asm volatile("" ::: "memory");

    const float inv = 1.0f / s;
    cesum += (m + __logf(s) - lt);  // -log p(target)

    m2[k] = m; inv2[k] = inv; fmw2[k] = fmw; bits2[k] = bits;
  }

  // ---- mask_low writes (bits/fmw only; store order irrelevant) ----
  if (low) {
#pragma unroll
    for (int k = 0; k < 2; ++k) {
      const int p = p0 + t + (k << 8);
      const int fmw = fmw2[k];
      const uint32_t bits = bits2[k];
#pragma unroll
      for (int c = 0; c < 27; ++c) {
        float mf;
        if (c == 0) mf = (float)(1 - fmw);
        else mf = (float)(((bits >> (c - 1)) & 1u) & (uint32_t)fmw);
        mout[(size_t)c * 1024 + p] = mf;
      }
    }
  }

  asm volatile("" ::: "memory");  // phase boundary

  // ---- Phase B: chunked accumulation, 9 channels per group ----
  __shared__ float red[4][55];
#pragma unroll
  for (int g = 0; g < 3; ++g) {
    float aS[9], aI[9];
#pragma unroll
    for (int j = 0; j < 9; ++j) { aS[j] = 0.0f; aI[j] = 0.0f; }
#pragma unroll
    for (int k = 0; k < 2; ++k) {
      const int p = p0 + t + (k << 8);
      const float m = m2[k], inv = inv2[k];
      const int fmw = fmw2[k];
      const uint32_t bits = bits2[k];
      const float* cp = cfb + p;
#pragma unroll
      for (int j = 0; j < 9; ++j) {
        const int c = g * 9 + j;
        const float v = cp[(size_t)c * HW];
        const float prob = __expf(v - m) * inv;  // bit-identical recompute
        aS[j] += prob;
        float mf;
        if (c == 0) mf = (float)(1 - fmw);
        else mf = (float)(((bits >> (c - 1)) & 1u) & (uint32_t)fmw);
        aI[j] += prob * mf;
      }
    }
    // One wave-reduction per group per block (R2's exact butterfly).
#pragma unroll
    for (int j = 0; j < 9; ++j) {
      const float rI = wave_reduce_add(aI[j]);
      const float rS = wave_reduce_add(aS[j]);
      if (lane == 0) {
        red[wave][g * 9 + j] = rI;
        red[wave][27 + g * 9 + j] = rS;
      }
    }
    asm volatile("" ::: "memory");  // group boundary: keep live sets small
  }
  cesum = wave_reduce_add(cesum);
  if (lane == 0) red[wave][54] = cesum;
  __syncthreads();
  if (t < 55) {
    const float v = red[0][t] + red[1][t] + red[2][t] + red[3][t];
    if (t == 54) atomicAdd(&ce[low ? 0 : 1], v);
    else atomicAdd(&acc[(size_t)b * 81 + t], v);
  }
}

// Final: block 0 -> loss_low (out[0]), block 1 -> loss_middle (out[1]).
__global__ __launch_bounds__(256) void final_kernel(
    const float* __restrict__ acc_mid,
    const float* __restrict__ acc_low,
    const float* __restrict__ ce,
    const int* __restrict__ length,
    float* __restrict__ out) {
  const int B = blockIdx.x;  // 0=low, 1=mid
  const float* acc = (B == 0) ? acc_low : acc_mid;
  const float hw = (B == 0) ? 1024.0f : 4096.0f;
  const int t = threadIdx.x;
  float dsum = 0.0f;
  for (int b = t; b < 512; b += 256) {
    const int lens = length[b] - 1;
    const float* a = acc + (size_t)b * 81;
    float d = 0.0f;
    for (int c = 1; c < 27; ++c) {
      const float I = a[c], S1 = a[27 + c], S2 = a[54 + c];
      const float score = (2.0f * I + 1.0f) / (S1 + S2 + 1.0f);
      if (c <= lens) d += (1.0f - score);
    }
    dsum += d / (float)lens;
  }
  __shared__ float red[4];
  const int wave = t >> 6, lane = t & 63;
  dsum = wave_reduce_add(dsum);
  if (lane == 0) red[wave] = dsum;
  __syncthreads();
  if (t == 0) {
    const float dice = red[0] + red[1] + red[2] + red[3];
    out[B] = dice * (1.0f / 512.0f) + ce[B] * (1.0f / (512.0f * hw));
  }
}

extern "C" void kernel_launch(void* const* d_in, const int* in_sizes, int n_in,
                              void* d_out, int out_size, void* d_ws, size_t ws_size,
                              hipStream_t stream) {
  const float* cf_mid = (const float*)d_in[0];  // [512,27,32,128]
  const float* cf_low = (const float*)d_in[1];  // [512,27,16,64]
  const float* attn   = (const float*)d_in[2];  // [512,26,32]
  const float* fore   = (const float*)d_in[3];  // [512,1,32,128]
  const int*   length = (const int*)d_in[4];    // [512]
  const float* alpha  = (const float*)d_in[5];  // scalar
  float* out = (float*)d_out;

  // ws layout
  uint32_t* bits_mid = (uint32_t*)d_ws;                   // 512*128
  uint32_t* bits_low = bits_mid + 512 * 128;              // 512*64
  float* acc_mid = (float*)(bits_low + 512 * 64);         // 512*81
  float* acc_low = acc_mid + 512 * 81;                    // 512*81
  float* ce = acc_low + 512 * 81;                         // 2

  hipLaunchKernelGGL(prep_kernel, dim3(512), dim3(192), 0, stream,
                     attn, fore, length, alpha, bits_mid, bits_low,
                     acc_mid, acc_low, ce);
  hipLaunchKernelGGL(main_kernel, dim3(5120), dim3(256), 0, stream,
                     cf_mid, cf_low, fore, out, bits_mid, bits_low,
                     acc_mid, acc_low, ce);
  hipLaunchKernelGGL(final_kernel, dim3(2), dim3(256), 0, stream,
                     acc_mid, acc_low, ce, length, out);
}